// Round 1
// baseline (809.863 us; speedup 1.0000x reference)
//
#include <hip/hip_runtime.h>

// Problem constants (match reference)
#define NB   4096      // batch
#define NT   256       // steps
#define ND   64        // state dim
#define CT   16        // chunk of steps computed per phase-A pass
#define NCH  (NT / CT)

// DPP row rotate-right by 1: lane i receives lane ((i-1)&15) of its 16-lane row.
// (Same convention as __shfl_up(x,1) / row_shr:1 bringing lower-lane values up.)
__device__ __forceinline__ float ror16(float x) {
  return __int_as_float(__builtin_amdgcn_update_dpp(
      0, __float_as_int(x), 0x121 /*row_ror:1*/, 0xF, 0xF, false));
}

// ds_swizzle xor patterns (BitMode: (xor<<10)|0x1F), stay within 8-lane groups
#define SWZ(x, patt) __int_as_float(__builtin_amdgcn_ds_swizzle(__float_as_int(x), (patt)))
#define SWZ_X1(x) SWZ(x, 0x041F)
#define SWZ_X2(x) SWZ(x, 0x081F)
#define SWZ_X4(x) SWZ(x, 0x101F)

// Rotation-MAC over a distributed 32-vector (vl = v[(s-r)&15], vh = v[16+((s-r)&15)])
#define ROTMAC(WA, WB, WC, WD)                          \
  _Pragma("unroll")                                     \
  for (int r = 0; r < 16; ++r) {                        \
    a0 = fmaf(vl, WA[r], a0);                           \
    a1 = fmaf(vh, WB[r], a1);                           \
    a2 = fmaf(vl, WC[r], a2);                           \
    a3 = fmaf(vh, WD[r], a3);                           \
    if (r < 15) { vl = ror16(vl); vh = ror16(vh); }     \
  }

__global__ __launch_bounds__(256, 1)
void enc_kernel(const float* __restrict__ S,   // states  [B][T][64]
                const float* __restrict__ G,   // gumbel  [B][T][32]
                const float* __restrict__ W1,  // [96][32]
                const float* __restrict__ b1,  // [32]
                const float* __restrict__ W2,  // [32][32]
                const float* __restrict__ b2,  // [32]
                const float* __restrict__ W3,  // [32][32]
                const float* __restrict__ b3,  // [32]
                float* __restrict__ out) {     // [B][T][32]
  // Per-wave private LDS slice: 64 rows (4 batches x 16 steps) x 32 (+1 pad)
  __shared__ float ldsH[4][64][33];

  const int tid  = threadIdx.x;
  const int wave = tid >> 6;
  const int lane = tid & 63;
  const int bw   = lane >> 4;        // batch-in-wave (0..3) == 16-lane DPP row
  const int s    = lane & 15;        // lane-in-row; owns neurons j0=s, j1=s+16
  const int b    = blockIdx.x * 16 + wave * 4 + bw;

  // ---- Preload rotation-ordered weight columns into VGPRs (once) ----
  float w1A[16], w1B[16], w1C[16], w1D[16];   // W1 rows 64..95 (c-part)
  float w2A[16], w2B[16], w2C[16], w2D[16];
  float w3A[16], w3B[16], w3C[16], w3D[16];
#pragma unroll
  for (int r = 0; r < 16; ++r) {
    const int klo = (s - r) & 15;
    const int khi = klo + 16;
    w1A[r] = W1[(64 + klo) * 32 + s];
    w1B[r] = W1[(64 + khi) * 32 + s];
    w1C[r] = W1[(64 + klo) * 32 + s + 16];
    w1D[r] = W1[(64 + khi) * 32 + s + 16];
    w2A[r] = W2[klo * 32 + s];
    w2B[r] = W2[khi * 32 + s];
    w2C[r] = W2[klo * 32 + s + 16];
    w2D[r] = W2[khi * 32 + s + 16];
    w3A[r] = W3[klo * 32 + s];
    w3B[r] = W3[khi * 32 + s];
    w3C[r] = W3[klo * 32 + s + 16];
    w3D[r] = W3[khi * 32 + s + 16];
  }
  const float b2l = b2[s], b2h = b2[s + 16];
  const float b3l = b3[s], b3h = b3[s + 16];

  // Initial carry: one_hot(0) per group of 8 -> c[k]=1 at k=0,8,16,24
  float clo = (s == 0 || s == 8) ? 1.f : 0.f;   // c[s]
  float chi = clo;                               // c[s+16]

  // Gumbel software pipeline (2 steps ahead)
  const size_t gbase = ((size_t)b * NT) * 32 + s;
  float gA0 = G[gbase + 0 * 32], gA1 = G[gbase + 0 * 32 + 16];
  float gB0 = G[gbase + 1 * 32], gB1 = G[gbase + 1 * 32 + 16];

  float* outp = out + ((size_t)b * NT) * 32 + s;
  float* myrow = &ldsH[wave][lane][0];   // phase-A write row: (bw, t_local=s)
  const int rbase = bw * 16;             // phase-B read rows for my batch

#pragma unroll 1
  for (int ch = 0; ch < NCH; ++ch) {
    // ================= Phase A: h1pre = states . W1[0:64] + b1 ==========
    {
      // lane -> row (batch b, t = ch*CT + s)
      const float* srow = S + ((size_t)b * NT + (ch * CT + s)) * ND;
      float4 xs[16];
#pragma unroll
      for (int i = 0; i < 16; ++i) xs[i] = ((const float4*)srow)[i];
      float acc[32];
#pragma unroll
      for (int j = 0; j < 32; ++j) acc[j] = 0.f;
#pragma unroll
      for (int k4 = 0; k4 < 16; ++k4) {
        const float xv[4] = {xs[k4].x, xs[k4].y, xs[k4].z, xs[k4].w};
#pragma unroll
        for (int kk = 0; kk < 4; ++kk) {
          const int k = k4 * 4 + kk;
          const float xk = xv[kk];
#pragma unroll
          for (int j = 0; j < 32; ++j)
            acc[j] = fmaf(xk, W1[k * 32 + j], acc[j]);   // W1 uniform -> s_load
        }
      }
#pragma unroll
      for (int j = 0; j < 32; ++j) myrow[j] = acc[j] + b1[j];
    }

    // ================= Phase B: sequential recurrence ====================
    float h1c0 = ldsH[wave][rbase + 0][s];
    float h1c1 = ldsH[wave][rbase + 0][s + 16];
#pragma unroll 1
    for (int tc = 0; tc < CT; ++tc) {
      const int t = ch * CT + tc;
      // prefetch next-step h1pre (clamped; re-read harmless)
      const int tn = (tc < CT - 1) ? tc + 1 : tc;
      const float h1n0 = ldsH[wave][rbase + tn][s];
      const float h1n1 = ldsH[wave][rbase + tn][s + 16];
      // prefetch gumbel t+2
      const int tg = (t + 2 < NT) ? t + 2 : NT - 1;
      const float gC0 = G[gbase + (size_t)tg * 32];
      const float gC1 = G[gbase + (size_t)tg * 32 + 16];

      // ---- layer 1 c-part: h1 = h1pre + c . W1[64:96] ----
      float a0 = h1c0, a1 = 0.f, a2 = h1c1, a3 = 0.f;
      float vl = clo, vh = chi;
      ROTMAC(w1A, w1B, w1C, w1D)
      float hl = fmaxf(a0 + a1, 0.f);
      float hh = fmaxf(a2 + a3, 0.f);

      // ---- layer 2 ----
      a0 = b2l; a1 = 0.f; a2 = b2h; a3 = 0.f; vl = hl; vh = hh;
      ROTMAC(w2A, w2B, w2C, w2D)
      hl = fmaxf(a0 + a1, 0.f);
      hh = fmaxf(a2 + a3, 0.f);

      // ---- layer 3 + gumbel ----
      a0 = b3l + gA0; a1 = 0.f; a2 = b3h + gA1; a3 = 0.f; vl = hl; vh = hh;
      ROTMAC(w3A, w3B, w3C, w3D)
      const float q0 = a0 + a1;
      const float q1 = a2 + a3;

      // ---- argmax over 8-lane groups (tau>0 monotone; softmax skipped) ----
      float m0 = q0, m1 = q1;
      m0 = fmaxf(m0, SWZ_X1(m0)); m1 = fmaxf(m1, SWZ_X1(m1));
      m0 = fmaxf(m0, SWZ_X2(m0)); m1 = fmaxf(m1, SWZ_X2(m1));
      m0 = fmaxf(m0, SWZ_X4(m0)); m1 = fmaxf(m1, SWZ_X4(m1));
      const unsigned long long bl0 = __ballot(q0 == m0);
      const unsigned long long bl1 = __ballot(q1 == m1);
      const int sh = lane & 56;        // group base within wave
      const unsigned gr0 = (unsigned)(bl0 >> sh) & 255u;
      const unsigned gr1 = (unsigned)(bl1 >> sh) & 255u;
      const int my = lane & 7;
      const float y0 = ((__ffs(gr0) - 1) == my) ? 1.f : 0.f;  // first-max tie-break
      const float y1 = ((__ffs(gr1) - 1) == my) ? 1.f : 0.f;

      // store y (== y_hard within 2^-24 of reference)
      outp[(size_t)t * 32]      = y0;
      outp[(size_t)t * 32 + 16] = y1;

      // advance pipelines / carry
      clo = y0; chi = y1;
      h1c0 = h1n0; h1c1 = h1n1;
      gA0 = gB0; gA1 = gB1; gB0 = gC0; gB1 = gC1;
    }
  }
}

extern "C" void kernel_launch(void* const* d_in, const int* in_sizes, int n_in,
                              void* d_out, int out_size, void* d_ws, size_t ws_size,
                              hipStream_t stream) {
  const float* S  = (const float*)d_in[0];
  const float* G  = (const float*)d_in[1];
  // d_in[2] = tau (==1.0; argmax invariant for any tau>0 -> unused)
  const float* W1 = (const float*)d_in[3];
  const float* b1 = (const float*)d_in[4];
  const float* W2 = (const float*)d_in[5];
  const float* b2 = (const float*)d_in[6];
  const float* W3 = (const float*)d_in[7];
  const float* b3 = (const float*)d_in[8];
  float* out = (float*)d_out;

  // 256 blocks x 256 threads = 1024 waves (1/SIMD by design: register-resident weights)
  hipLaunchKernelGGL(enc_kernel, dim3(NB / 16), dim3(256), 0, stream,
                     S, G, W1, b1, W2, b2, W3, b3, out);
}

// Round 2
// 777.100 us; speedup vs baseline: 1.0422x; 1.0422x over previous
//
#include <hip/hip_runtime.h>

// Problem constants (match reference)
#define NB   4096      // batch
#define NT   256       // steps
#define ND   64        // state dim

// ---------------- DPP helpers ----------------
template <int CTRL>
__device__ __forceinline__ float dppf(float x) {
  return __int_as_float(__builtin_amdgcn_update_dpp(
      0, __float_as_int(x), CTRL, 0xF, 0xF, false));
}
// row rotate-right by 1 within 16-lane rows: lane i gets lane (i-1)&15
#define ROR16(x) dppf<0x121>(x)
// max over 8-lane group, pure VALU (no LDS pipe):
//   quad_perm(1,0,3,2)=0xB1, quad_perm(2,3,0,1)=0x4E, row_half_mirror=0x141
__device__ __forceinline__ float max8(float x) {
  float t = fmaxf(x, dppf<0xB1>(x));
  t = fmaxf(t, dppf<0x4E>(t));
  t = fmaxf(t, dppf<0x141>(t));
  return t;
}

// Rotation-MAC over a distributed 32-vector (vl = v[(s-r)&15], vh = v[16+((s-r)&15)])
#define ROTMAC(WA, WB, WC, WD)                          \
  _Pragma("unroll")                                     \
  for (int r = 0; r < 16; ++r) {                        \
    a0 = fmaf(vl, WA[r], a0);                           \
    a1 = fmaf(vh, WB[r], a1);                           \
    a2 = fmaf(vl, WC[r], a2);                           \
    a3 = fmaf(vh, WD[r], a3);                           \
    if (r < 15) { vl = ROR16(vl); vh = ROR16(vh); }     \
  }

// ===================== Kernel A =====================
// h1pre[b][t][j] = states[b][t][:] . W1[0:64][j] + b1[j]  -> written into `out`
// One thread per (b,t) row. ~60 VGPRs, high occupancy, HBM-bound.
__global__ __launch_bounds__(256)
void h1pre_kernel(const float* __restrict__ S,
                  const float* __restrict__ W1,
                  const float* __restrict__ b1,
                  float* __restrict__ out) {
  const int row = blockIdx.x * 256 + threadIdx.x;     // 0 .. B*T-1
  const float4* srow = (const float4*)(S + (size_t)row * ND);

  float acc[32];
#pragma unroll
  for (int j = 0; j < 32; ++j) acc[j] = b1[j];        // uniform -> s_load

#pragma unroll
  for (int kc = 0; kc < 4; ++kc) {                    // 4 chunks of 16 k
    float4 x[4];
#pragma unroll
    for (int i = 0; i < 4; ++i) x[i] = srow[kc * 4 + i];
#pragma unroll
    for (int i = 0; i < 4; ++i) {
      const float xv[4] = {x[i].x, x[i].y, x[i].z, x[i].w};
#pragma unroll
      for (int kk = 0; kk < 4; ++kk) {
        const int k = kc * 16 + i * 4 + kk;
        const float xk = xv[kk];
#pragma unroll
        for (int j = 0; j < 32; ++j)
          acc[j] = fmaf(xk, W1[k * 32 + j], acc[j]);  // W1 uniform -> s_load
      }
    }
  }

  float4* orow = (float4*)(out + (size_t)row * 32);
#pragma unroll
  for (int j4 = 0; j4 < 8; ++j4)
    orow[j4] = make_float4(acc[4 * j4], acc[4 * j4 + 1],
                           acc[4 * j4 + 2], acc[4 * j4 + 3]);
}

// ===================== Kernel B =====================
// Sequential recurrence. Wave = 4 batches x 16 lanes; lane owns neurons s, s+16.
// All recurrent weights (192 floats) resident in VGPRs, rotation-ordered.
// Reads h1pre from `out`, overwrites with y in place (read-before-write per t).
__global__ __launch_bounds__(256, 1)
void rec_kernel(const float* __restrict__ G,   // gumbel  [B][T][32]
                const float* __restrict__ W1,  // [96][32] (rows 64..95 used)
                const float* __restrict__ W2,  // [32][32]
                const float* __restrict__ b2,  // [32]
                const float* __restrict__ W3,  // [32][32]
                const float* __restrict__ b3,  // [32]
                float* __restrict__ out) {     // in: h1pre, out: y  [B][T][32]
  const int tid  = threadIdx.x;
  const int wave = tid >> 6;
  const int lane = tid & 63;
  const int bw   = lane >> 4;        // batch-in-wave (0..3) == 16-lane DPP row
  const int s    = lane & 15;        // lane-in-row; owns neurons s, s+16
  const int b    = blockIdx.x * 16 + wave * 4 + bw;

  // ---- rotation-ordered weight columns -> VGPRs (once) ----
  float w1A[16], w1B[16], w1C[16], w1D[16];   // W1 rows 64..95 (c-part)
  float w2A[16], w2B[16], w2C[16], w2D[16];
  float w3A[16], w3B[16], w3C[16], w3D[16];
#pragma unroll
  for (int r = 0; r < 16; ++r) {
    const int klo = (s - r) & 15;
    const int khi = klo + 16;
    w1A[r] = W1[(64 + klo) * 32 + s];
    w1B[r] = W1[(64 + khi) * 32 + s];
    w1C[r] = W1[(64 + klo) * 32 + s + 16];
    w1D[r] = W1[(64 + khi) * 32 + s + 16];
    w2A[r] = W2[klo * 32 + s];
    w2B[r] = W2[khi * 32 + s];
    w2C[r] = W2[klo * 32 + s + 16];
    w2D[r] = W2[khi * 32 + s + 16];
    w3A[r] = W3[klo * 32 + s];
    w3B[r] = W3[khi * 32 + s];
    w3C[r] = W3[klo * 32 + s + 16];
    w3D[r] = W3[khi * 32 + s + 16];
  }
  const float b2l = b2[s], b2h = b2[s + 16];
  const float b3l = b3[s], b3h = b3[s + 16];

  // initial carry: one_hot(0) per 8-group -> c[k]=1 at k=0,8,16,24
  float clo = (s == 0 || s == 8) ? 1.f : 0.f;
  float chi = clo;

  // ---- software pipelines, distance 2 ----
  const size_t gbase = ((size_t)b * NT) * 32 + s;
  const size_t obase = ((size_t)b * NT) * 32 + s;
  float gA0 = G[gbase + 0 * 32], gA1 = G[gbase + 0 * 32 + 16];
  float gB0 = G[gbase + 1 * 32], gB1 = G[gbase + 1 * 32 + 16];
  float hA0 = out[obase + 0 * 32], hA1 = out[obase + 0 * 32 + 16];
  float hB0 = out[obase + 1 * 32], hB1 = out[obase + 1 * 32 + 16];

#pragma unroll 1
  for (int t = 0; t < NT; ++t) {
    // prefetch t+2 (clamped; garbage at tail is discarded by the pipeline)
    const int tp = (t + 2 < NT) ? t + 2 : NT - 1;
    const float hC0 = out[obase + (size_t)tp * 32];
    const float hC1 = out[obase + (size_t)tp * 32 + 16];
    const float gC0 = G[gbase + (size_t)tp * 32];
    const float gC1 = G[gbase + (size_t)tp * 32 + 16];

    // ---- layer 1 c-part: h1 = h1pre + c . W1[64:96] ----
    float a0 = hA0, a1 = 0.f, a2 = hA1, a3 = 0.f;
    float vl = clo, vh = chi;
    ROTMAC(w1A, w1B, w1C, w1D)
    float hl = fmaxf(a0 + a1, 0.f);
    float hh = fmaxf(a2 + a3, 0.f);

    // ---- layer 2 ----
    a0 = b2l; a1 = 0.f; a2 = b2h; a3 = 0.f; vl = hl; vh = hh;
    ROTMAC(w2A, w2B, w2C, w2D)
    hl = fmaxf(a0 + a1, 0.f);
    hh = fmaxf(a2 + a3, 0.f);

    // ---- layer 3 + gumbel ----
    a0 = b3l + gA0; a1 = 0.f; a2 = b3h + gA1; a3 = 0.f; vl = hl; vh = hh;
    ROTMAC(w3A, w3B, w3C, w3D)
    const float q0 = a0 + a1;
    const float q1 = a2 + a3;

    // ---- argmax over 8-lane groups, pure DPP (tau>0 monotone) ----
    const float m0 = max8(q0);
    const float m1 = max8(q1);
    const unsigned long long bl0 = __ballot(q0 == m0);
    const unsigned long long bl1 = __ballot(q1 == m1);
    const int sh = lane & 56;
    const unsigned gr0 = (unsigned)(bl0 >> sh) & 255u;
    const unsigned gr1 = (unsigned)(bl1 >> sh) & 255u;
    const int my = lane & 7;
    const float y0 = ((__ffs(gr0) - 1) == my) ? 1.f : 0.f;  // first-max tie-break
    const float y1 = ((__ffs(gr1) - 1) == my) ? 1.f : 0.f;

    out[obase + (size_t)t * 32]      = y0;
    out[obase + (size_t)t * 32 + 16] = y1;

    clo = y0; chi = y1;
    hA0 = hB0; hA1 = hB1; hB0 = hC0; hB1 = hC1;
    gA0 = gB0; gA1 = gB1; gB0 = gC0; gB1 = gC1;
  }
}

extern "C" void kernel_launch(void* const* d_in, const int* in_sizes, int n_in,
                              void* d_out, int out_size, void* d_ws, size_t ws_size,
                              hipStream_t stream) {
  const float* S  = (const float*)d_in[0];
  const float* G  = (const float*)d_in[1];
  // d_in[2] = tau (==1.0; argmax invariant for any tau>0 -> unused)
  const float* W1 = (const float*)d_in[3];
  const float* b1 = (const float*)d_in[4];
  const float* W2 = (const float*)d_in[5];
  const float* b2 = (const float*)d_in[6];
  const float* W3 = (const float*)d_in[7];
  const float* b3 = (const float*)d_in[8];
  float* out = (float*)d_out;

  // Kernel A: h1pre -> out  (B*T = 1,048,576 rows)
  hipLaunchKernelGGL(h1pre_kernel, dim3((NB * NT) / 256), dim3(256), 0, stream,
                     S, W1, b1, out);
  // Kernel B: sequential recurrence, in-place on out
  hipLaunchKernelGGL(rec_kernel, dim3(NB / 16), dim3(256), 0, stream,
                     G, W1, W2, b2, W3, b3, out);
}

// Round 3
// 764.509 us; speedup vs baseline: 1.0593x; 1.0165x over previous
//
#include <hip/hip_runtime.h>

// Problem constants (match reference)
#define NB   4096      // batch
#define NT   256       // steps
#define ND   64        // state dim

// ---------------- cross-lane helpers ----------------
// row_ror:R within 16-lane rows, bound_ctrl=1 (no invalid lanes for ror -> identical
// semantics, and makes the mov_dpp foldable into v_fmac_f32_dpp).
template <int CTRL>
__device__ __forceinline__ float rotr(float x) {
  return __int_as_float(__builtin_amdgcn_update_dpp(
      0, __float_as_int(x), CTRL, 0xF, 0xF, true));
}
// lane ^ 16 within 32-lane groups (BitMode: xor_mask=0x10<<10 | and_mask=0x1F)
__device__ __forceinline__ float swz16(float x) {
  return __int_as_float(__builtin_amdgcn_ds_swizzle(__float_as_int(x), 0x401F));
}
// max over 8-lane groups, pure DPP (quad_perm 1,0,3,2 / 2,3,0,1 / row_half_mirror)
template <int CTRL>
__device__ __forceinline__ float dppf(float x) {
  return __int_as_float(__builtin_amdgcn_update_dpp(
      0, __float_as_int(x), CTRL, 0xF, 0xF, true));
}
__device__ __forceinline__ float max8(float x) {
  float t = fmaxf(x, dppf<0xB1>(x));
  t = fmaxf(t, dppf<0x4E>(t));
  t = fmaxf(t, dppf<0x141>(t));
  return t;
}

// One rotation-term: acc += row_ror<r>(v) * w[r]   (independent DPP per r, no chain)
#define RSTEP(r, acc, v, w) acc = fmaf(rotr<0x120 + r>(v), w[r], acc)

// Full 32-MAC layer for one output neuron per lane (two 16-rotations, 4 acc chains)
#define LAYER16(vA, vB, wA, wB, initA, q)                  \
  {                                                        \
    float a0 = (initA), a1 = 0.f, c0 = 0.f, c1 = 0.f;      \
    a0 = fmaf((vA), wA[0], a0);                            \
    c0 = fmaf((vB), wB[0], c0);                            \
    RSTEP(1, a1, vA, wA);  RSTEP(1, c1, vB, wB);           \
    RSTEP(2, a0, vA, wA);  RSTEP(2, c0, vB, wB);           \
    RSTEP(3, a1, vA, wA);  RSTEP(3, c1, vB, wB);           \
    RSTEP(4, a0, vA, wA);  RSTEP(4, c0, vB, wB);           \
    RSTEP(5, a1, vA, wA);  RSTEP(5, c1, vB, wB);           \
    RSTEP(6, a0, vA, wA);  RSTEP(6, c0, vB, wB);           \
    RSTEP(7, a1, vA, wA);  RSTEP(7, c1, vB, wB);           \
    RSTEP(8, a0, vA, wA);  RSTEP(8, c0, vB, wB);           \
    RSTEP(9, a1, vA, wA);  RSTEP(9, c1, vB, wB);           \
    RSTEP(10, a0, vA, wA); RSTEP(10, c0, vB, wB);          \
    RSTEP(11, a1, vA, wA); RSTEP(11, c1, vB, wB);          \
    RSTEP(12, a0, vA, wA); RSTEP(12, c0, vB, wB);          \
    RSTEP(13, a1, vA, wA); RSTEP(13, c1, vB, wB);          \
    RSTEP(14, a0, vA, wA); RSTEP(14, c0, vB, wB);          \
    RSTEP(15, a1, vA, wA); RSTEP(15, c1, vB, wB);          \
    q = (a0 + a1) + (c0 + c1);                             \
  }

// ===================== Kernel A =====================
// h1pre[b][t][j] = states[b][t][:] . W1[0:64][j] + b1[j]  -> written into `out`.
// TWO rows per thread: doubles FMAs per uniform-W1 s_load stream.
__global__ __launch_bounds__(256)
void h1pre_kernel(const float* __restrict__ S,
                  const float* __restrict__ W1,
                  const float* __restrict__ b1,
                  float* __restrict__ out) {
  const size_t pid = (size_t)blockIdx.x * 256 + threadIdx.x;  // 0 .. B*T/2-1
  const float4* s0 = (const float4*)(S + pid * 2 * ND);
  const float4* s1 = s0 + (ND / 4);

  float acc0[32], acc1[32];
#pragma unroll
  for (int j = 0; j < 32; ++j) { acc0[j] = b1[j]; acc1[j] = b1[j]; }

#pragma unroll
  for (int kc = 0; kc < 4; ++kc) {
    float4 x0[4], x1[4];
#pragma unroll
    for (int i = 0; i < 4; ++i) { x0[i] = s0[kc * 4 + i]; x1[i] = s1[kc * 4 + i]; }
#pragma unroll
    for (int i = 0; i < 4; ++i) {
      const float v0[4] = {x0[i].x, x0[i].y, x0[i].z, x0[i].w};
      const float v1[4] = {x1[i].x, x1[i].y, x1[i].z, x1[i].w};
#pragma unroll
      for (int kk = 0; kk < 4; ++kk) {
        const int k = kc * 16 + i * 4 + kk;
#pragma unroll
        for (int j = 0; j < 32; ++j) {
          const float w = W1[k * 32 + j];                 // uniform -> s_load
          acc0[j] = fmaf(v0[kk], w, acc0[j]);
          acc1[j] = fmaf(v1[kk], w, acc1[j]);
        }
      }
    }
  }

  float4* o0 = (float4*)(out + pid * 2 * 32);
  float4* o1 = o0 + 8;
#pragma unroll
  for (int q = 0; q < 8; ++q) {
    o0[q] = make_float4(acc0[4*q], acc0[4*q+1], acc0[4*q+2], acc0[4*q+3]);
    o1[q] = make_float4(acc1[4*q], acc1[4*q+1], acc1[4*q+2], acc1[4*q+3]);
  }
}

// ===================== Kernel B =====================
// Wave = 2 batches x 32 lanes. Lane owns neuron j = (lane&15) + 16*halfbit and
// carries the activation PAIR (h_j, h_{j^16}); the half-swap for odd rows is
// baked into the weight preload order. 96 weight VGPRs/lane, no AGPR shuffling.
__global__ __launch_bounds__(256, 2)
void rec_kernel(const float* __restrict__ G,   // gumbel  [B][T][32]
                const float* __restrict__ W1,  // [96][32] (rows 64..95 used)
                const float* __restrict__ W2,  // [32][32]
                const float* __restrict__ b2,  // [32]
                const float* __restrict__ W3,  // [32][32]
                const float* __restrict__ b3,  // [32]
                float* __restrict__ out) {     // in: h1pre, out: y  [B][T][32]
  const int tid  = threadIdx.x;
  const int wave = tid >> 6;
  const int lane = tid & 63;
  const int s    = lane & 15;
  const int half = (lane >> 4) & 1;            // row parity within 32-lane group
  const int j    = s + 16 * half;              // owned neuron
  const int b    = blockIdx.x * 8 + wave * 2 + (lane >> 5);

  // Rotation-ordered weights. vA at rotation r carries h_{kA(r)}, vB h_{kB(r)}.
  float w1A[16], w1B[16], w2A[16], w2B[16], w3A[16], w3B[16];
#pragma unroll
  for (int r = 0; r < 16; ++r) {
    const int kA = ((s - r) & 15) + 16 * half;        // own-half k index
    const int kB = ((s - r) & 15) + 16 * (1 - half);  // other-half k index
    w1A[r] = W1[(64 + kA) * 32 + j];
    w1B[r] = W1[(64 + kB) * 32 + j];
    w2A[r] = W2[kA * 32 + j];
    w2B[r] = W2[kB * 32 + j];
    w3A[r] = W3[kA * 32 + j];
    w3B[r] = W3[kB * 32 + j];
  }
  const float b2j = b2[j];
  const float b3j = b3[j];

  // Initial carry pair: c = one_hot(0) per 8-group -> c_k=1 iff k%8==0.
  // Both c_j and c_{j^16} share the (s%8==0) criterion.
  float vA = (s % 8 == 0) ? 1.f : 0.f;
  float vB = vA;

  // software pipeline, distance 2 (gumbel + h1pre, 1 dword/lane/step, coalesced)
  const size_t base = ((size_t)b * NT) * 32 + j;
  float gA = G[base], gB = G[base + 32];
  float hA = out[base], hB = out[base + 32];

#pragma unroll 1
  for (int t = 0; t < NT; ++t) {
    const int tp = (t + 2 < NT) ? t + 2 : NT - 1;
    const float gC = G[base + (size_t)tp * 32];
    const float hC = out[base + (size_t)tp * 32];

    float q;
    // L1: h1 = relu(h1pre + c . W1[64:96])
    LAYER16(vA, vB, w1A, w1B, hA, q);
    float tq = swz16(q);
    float xA = fmaxf(q, 0.f), xB = fmaxf(tq, 0.f);
    // L2
    LAYER16(xA, xB, w2A, w2B, b2j, q);
    tq = swz16(q);
    xA = fmaxf(q, 0.f); xB = fmaxf(tq, 0.f);
    // L3 (+ gumbel; tau=1>0 monotone, softmax skipped)
    LAYER16(xA, xB, w3A, w3B, b3j + gA, q);

    // argmax over 8-lane groups; first-max tie-break matches np.argmax
    const float m = max8(q);
    const unsigned long long bl = __ballot(q == m);
    const unsigned gr = (unsigned)(bl >> (lane & 56)) & 255u;
    const float y = ((__ffs(gr) - 1) == (lane & 7)) ? 1.f : 0.f;

    out[base + (size_t)t * 32] = y;    // coalesced: 64 lanes = 2 full rows

    // carry for next step (same baked half-swap convention as activations)
    vA = y;
    vB = swz16(y);
    hA = hB; hB = hC; gA = gB; gB = gC;
  }
}

extern "C" void kernel_launch(void* const* d_in, const int* in_sizes, int n_in,
                              void* d_out, int out_size, void* d_ws, size_t ws_size,
                              hipStream_t stream) {
  const float* S  = (const float*)d_in[0];
  const float* G  = (const float*)d_in[1];
  // d_in[2] = tau (==1.0; argmax invariant for any tau>0 -> unused)
  const float* W1 = (const float*)d_in[3];
  const float* b1 = (const float*)d_in[4];
  const float* W2 = (const float*)d_in[5];
  const float* b2 = (const float*)d_in[6];
  const float* W3 = (const float*)d_in[7];
  const float* b3 = (const float*)d_in[8];
  float* out = (float*)d_out;

  // Kernel A: h1pre -> out. 2 rows/thread: B*T/2 threads.
  hipLaunchKernelGGL(h1pre_kernel, dim3((NB * NT / 2) / 256), dim3(256), 0, stream,
                     S, W1, b1, out);
  // Kernel B: recurrence, in-place on out. 8 batches/block -> 512 blocks,
  // 2048 waves = 2 waves/SIMD.
  hipLaunchKernelGGL(rec_kernel, dim3(NB / 8), dim3(256), 0, stream,
                     G, W1, W2, b2, W3, b3, out);
}

// Round 5
// 751.834 us; speedup vs baseline: 1.0772x; 1.0169x over previous
//
#include <hip/hip_runtime.h>

// Problem constants (match reference)
#define NB   4096      // batch
#define NT   256       // steps
#define ND   64        // state dim

// ---------------- cross-lane helpers ----------------
// DPP with full masks + bound_ctrl=1 (all lanes written -> fold-eligible)
template <int CTRL>
__device__ __forceinline__ float dppf(float x) {
  return __int_as_float(__builtin_amdgcn_update_dpp(
      0, __float_as_int(x), CTRL, 0xF, 0xF, true));
}
// full-wave pull: result = lane[addr>>2].x
__device__ __forceinline__ float bperm(int addr, float x) {
  return __int_as_float(__builtin_amdgcn_ds_bpermute(addr, __float_as_int(x)));
}
// max over 8-lane groups: quad_perm(1,0,3,2), quad_perm(2,3,0,1), row_half_mirror
__device__ __forceinline__ float max8(float x) {
  float t = fmaxf(x, dppf<0xB1>(x));
  t = fmaxf(t, dppf<0x4E>(t));
  t = fmaxf(t, dppf<0x141>(t));
  return t;
}

// 16-term rotation-MAC over a 16-lane DPP row (row_ror:r presents lane
// ((s-r)&15)'s value at lane s), two accumulator chains for ILP.
// PROPER FUNCTION, not a macro: round-4's macro version shadowed its own
// output name ("MAC16(p1,...)" collided with the internal p1 chain), leaving
// the result uninitialized. Function scoping makes that impossible.
__device__ __forceinline__ float mac16(float v, const float w[16], float init) {
  float a0 = fmaf(v, w[0], init);
  float a1 = dppf<0x121>(v) * w[1];
  a0 = fmaf(dppf<0x122>(v), w[2], a0);
  a1 = fmaf(dppf<0x123>(v), w[3], a1);
  a0 = fmaf(dppf<0x124>(v), w[4], a0);
  a1 = fmaf(dppf<0x125>(v), w[5], a1);
  a0 = fmaf(dppf<0x126>(v), w[6], a0);
  a1 = fmaf(dppf<0x127>(v), w[7], a1);
  a0 = fmaf(dppf<0x128>(v), w[8], a0);
  a1 = fmaf(dppf<0x129>(v), w[9], a1);
  a0 = fmaf(dppf<0x12A>(v), w[10], a0);
  a1 = fmaf(dppf<0x12B>(v), w[11], a1);
  a0 = fmaf(dppf<0x12C>(v), w[12], a0);
  a1 = fmaf(dppf<0x12D>(v), w[13], a1);
  a0 = fmaf(dppf<0x12E>(v), w[14], a0);
  a1 = fmaf(dppf<0x12F>(v), w[15], a1);
  return a0 + a1;
}

// ===================== Kernel A =====================
// h1pre[b][t][j] = states[b][t][:] . W1[0:64][j] + b1[j]  -> written into `out`.
// 1 row/thread; kc loop NOT unrolled so the ~4.5 KB body stays I$-resident.
__global__ __launch_bounds__(256)
void h1pre_kernel(const float* __restrict__ S,
                  const float* __restrict__ W1,
                  const float* __restrict__ b1,
                  float* __restrict__ out) {
  const size_t row = (size_t)blockIdx.x * 256 + threadIdx.x;   // 0 .. B*T-1
  const float4* srow = (const float4*)(S + row * ND);

  float acc[32];
#pragma unroll
  for (int j = 0; j < 32; ++j) acc[j] = b1[j];                 // uniform -> s_load

#pragma unroll 1
  for (int kc = 0; kc < 4; ++kc) {                             // resident loop body
    float4 x[4];
#pragma unroll
    for (int i = 0; i < 4; ++i) x[i] = srow[kc * 4 + i];
#pragma unroll
    for (int i = 0; i < 4; ++i) {
      const float xv[4] = {x[i].x, x[i].y, x[i].z, x[i].w};
#pragma unroll
      for (int kk = 0; kk < 4; ++kk) {
        const int k = kc * 16 + i * 4 + kk;
#pragma unroll
        for (int j = 0; j < 32; ++j)
          acc[j] = fmaf(xv[kk], W1[k * 32 + j], acc[j]);       // uniform -> s_load
      }
    }
  }

  float4* orow = (float4*)(out + row * 32);
#pragma unroll
  for (int q = 0; q < 8; ++q)
    orow[q] = make_float4(acc[4*q], acc[4*q+1], acc[4*q+2], acc[4*q+3]);
}

// ===================== Kernel B =====================
// Wave = ONE batch. lane = s + 16*g; g = (jhalf | khalf<<1); lane owns neuron
// j = s+16*jhalf restricted to k-range [16*khalf, 16*khalf+16). 48 weight
// floats/lane -> everything fits in arch VGPRs at 4 waves/SIMD (no AGPR moves).
// Per layer: 16 DPP-rotation MACs + xor-32 combine + khalf-aligned redistribute.
__global__ __launch_bounds__(256, 4)
void rec_kernel(const float* __restrict__ G,   // gumbel  [B][T][32]
                const float* __restrict__ W1,  // [96][32] (rows 64..95 used)
                const float* __restrict__ W2,  // [32][32]
                const float* __restrict__ b2,  // [32]
                const float* __restrict__ W3,  // [32][32]
                const float* __restrict__ b3,  // [32]
                float* __restrict__ out) {     // in: h1pre, out: y  [B][T][32]
  const int tid  = threadIdx.x;
  const int wave = tid >> 6;
  const int lane = tid & 63;
  const int s    = lane & 15;
  const int g    = lane >> 4;
  const int jh   = g & 1;
  const int kh   = g >> 1;
  const int j    = s + 16 * jh;          // owned neuron
  const int b    = blockIdx.x * 4 + wave;
  const bool lo  = (lane < 32);          // kh==0 rows (where j == lane)

  // rotation-ordered weights for this lane's (j, k-half)
  float w1[16], w2[16], w3[16];
#pragma unroll
  for (int r = 0; r < 16; ++r) {
    const int k = ((s - r) & 15) + 16 * kh;
    w1[r] = W1[(64 + k) * 32 + j];
    w2[r] = W2[k * 32 + j];
    w3[r] = W3[k * 32 + j];
  }
  // biases enter once (on kh==0 partials only)
  const float bias2 = lo ? b2[j] : 0.f;
  const float bias3 = lo ? b3[j] : 0.f;

  // bpermute byte-addresses (precomputed once)
  const int a_x32 = (lane ^ 32) << 2;          // xor-32 combine partner
  const int a_rd  = (s + 16 * kh) << 2;        // khalf-aligned redistribute src

  // carry, khalf-aligned: c_{s+16kh} = 1 iff (s+16kh)%8==0 <=> s%8==0
  float v = (s % 8 == 0) ? 1.f : 0.f;

  // software pipeline (distance 2): 1 dword/lane/step, lanes>=32 dup-load (L1 hit)
  const size_t base = ((size_t)b * NT) * 32 + (lane & 31);
  float hA = out[base], hB = out[base + 32];
  float gA = G[base],   gB = G[base + 32];

  const int sh = lane & 56;
  const int my = lane & 7;

#pragma unroll 1
  for (int t = 0; t < NT; ++t) {
    const int tp = (t + 2 < NT) ? t + 2 : NT - 1;
    const float hC = out[base + (size_t)tp * 32];
    const float gC = G[base + (size_t)tp * 32];

    // L1: q_j = h1pre_j + c . W1[64:96][:,j]
    const float p1 = mac16(v, w1, lo ? hA : 0.f);
    float q = p1 + bperm(a_x32, p1);           // combine k-halves
    v = bperm(a_rd, fmaxf(q, 0.f));            // relu + khalf-align

    // L2
    const float p2 = mac16(v, w2, bias2);
    q = p2 + bperm(a_x32, p2);
    v = bperm(a_rd, fmaxf(q, 0.f));

    // L3 (+ gumbel; tau=1>0 monotone, softmax skipped)
    const float p3 = mac16(v, w3, lo ? (bias3 + gA) : 0.f);
    q = p3 + bperm(a_x32, p3);

    // argmax over 8-lane groups; first-max tie-break matches np.argmax
    const float m = max8(q);
    const unsigned long long bl = __ballot(q == m);
    const unsigned gr = (unsigned)(bl >> sh) & 255u;
    const float y = ((__ffs(gr) - 1) == my) ? 1.f : 0.f;

    if (lo) out[base + (size_t)t * 32] = y;    // lanes 0-31: j == lane, coalesced

    v = bperm(a_rd, y);                        // next-step carry, khalf-aligned

    hA = hB; hB = hC; gA = gB; gB = gC;
  }
}

extern "C" void kernel_launch(void* const* d_in, const int* in_sizes, int n_in,
                              void* d_out, int out_size, void* d_ws, size_t ws_size,
                              hipStream_t stream) {
  const float* S  = (const float*)d_in[0];
  const float* G  = (const float*)d_in[1];
  // d_in[2] = tau (==1.0; argmax invariant for any tau>0 -> unused)
  const float* W1 = (const float*)d_in[3];
  const float* b1 = (const float*)d_in[4];
  const float* W2 = (const float*)d_in[5];
  const float* b2 = (const float*)d_in[6];
  const float* W3 = (const float*)d_in[7];
  const float* b3 = (const float*)d_in[8];
  float* out = (float*)d_out;

  // Kernel A: h1pre -> out. 1 row/thread, B*T threads.
  hipLaunchKernelGGL(h1pre_kernel, dim3((NB * NT) / 256), dim3(256), 0, stream,
                     S, W1, b1, out);
  // Kernel B: recurrence, in-place on out. 1 batch/wave -> 1024 blocks,
  // 4096 waves = 4 waves/SIMD.
  hipLaunchKernelGGL(rec_kernel, dim3(NB / 4), dim3(256), 0, stream,
                     G, W1, W2, b2, W3, b3, out);
}